// Round 5
// baseline (120.708 us; speedup 1.0000x reference)
//
#include <hip/hip_runtime.h>
#include <math.h>

#define TPB 256
#define SLOTS 4      // priors per fused thread (wave argmax covers 256 priors)
#define TPBS 512     // select block size (8 waves; R5: halves barrier cost)
#define NVREG 18     // register slots/thread in select (covers P <= 9216)

typedef unsigned long long ull;
typedef float pf4 __attribute__((ext_vector_type(4), aligned(4)));  // 4B-aligned float4

__device__ __forceinline__ float jac(float tx0, float ty0, float tx1, float ty1, float ta,
                                     float px0, float py0, float px1, float py1, float pa) {
    float ltx = fmaxf(tx0, px0), lty = fmaxf(ty0, py0);
    float rbx = fminf(tx1, px1), rby = fminf(ty1, py1);
    float w = fmaxf(rbx - ltx, 0.0f), h = fmaxf(rby - lty, 0.0f);
    float inter = w * h;
    return inter / (ta + pa - inter);
}

// R4: 4 priors/thread (slot s owns p = chunk*1024 + s*256 + tid).
//  - per-o argmax: one 6-level wave shuffle covers 256 priors; slot-ordered
//    ballots keep the exact smallest-p tie.
//  - part sums keep the 256-prior chunk granularity (one butterfly per slot,
//    same w=0..3 add order) -> every fp summation tree bit-identical.
//  - conf rows software-pipelined through rvA/rvB.
//  - per-chunk (1024-prior) top-byte histogram, u16-pair packed.
template <int ON, int CN>
__global__ __launch_bounds__(TPB) void fused_kernel(
    const float* __restrict__ loc, const float* __restrict__ priors,
    const float* __restrict__ targets, const float* __restrict__ conf,
    int P, int O_rt, int C_rt, int CB2,
    float* __restrict__ mined, ull* __restrict__ pkeys,
    float* __restrict__ part_ll, float* __restrict__ part_pc,
    int* __restrict__ part_np, unsigned* __restrict__ chist) {
    constexpr int OMAX = (ON > 0) ? ON : 64;
    constexpr int CC = (CN > 0) ? CN : 32;
    constexpr int WPB = TPB / 64;  // 4 waves per block
    const int O = (ON > 0) ? ON : O_rt;
    const int C = (CN > 0) ? CN : C_rt;
    const int b = blockIdx.x / CB2;
    const int chunk = blockIdx.x % CB2;
    const int tid = threadIdx.x;
    const int base = chunk * (TPB * SLOTS);
    const int lane = tid & 63, wv = tid >> 6;
    const int CB2P = CB2 * SLOTS;  // per-wave key entries / old-chunk parts

    __shared__ float s_tx0[OMAX], s_ty0[OMAX], s_tx1[OMAX], s_ty1[OMAX];
    __shared__ float s_lab[OMAX], s_area[OMAX];
    __shared__ int s_h[256];
    __shared__ float s_wll[WPB][SLOTS], s_wpc[WPB][SLOTS];
    __shared__ int s_wnp[WPB][SLOTS];

    int p_[SLOTS];
    bool pv_[SLOTS];
#pragma unroll
    for (int s = 0; s < SLOTS; ++s) { p_[s] = base + s * TPB + tid; pv_[s] = p_[s] < P; }

    // prior corners (issued first; cx/cy/pw/ph reloaded L2-hot in phase B)
    float px0[SLOTS], py0[SLOTS], px1[SLOTS], py1[SLOTS], pa[SLOTS];
#pragma unroll
    for (int s = 0; s < SLOTS; ++s) {
        float4 pr = pv_[s] ? ((const float4*)priors)[p_[s]] : make_float4(0.f, 0.f, 1.f, 1.f);
        px0[s] = pr.x - pr.z * 0.5f; py0[s] = pr.y - pr.w * 0.5f;
        px1[s] = pr.x + pr.z * 0.5f; py1[s] = pr.y + pr.w * 0.5f;
        pa[s] = (px1[s] - px0[s]) * (py1[s] - py0[s]);
    }

    float rvA[CC], rvB[CC];
    auto loadrow = [&](float* rv, int p) {
        const float* row = conf + ((size_t)b * P + p) * C;
        if (CN > 0) {
#pragma unroll
            for (int q = 0; q < CN / 4; ++q) {
                pf4 v = *(const pf4*)(row + 4 * q);
#pragma unroll
                for (int e = 0; e < 4; ++e) rv[4 * q + e] = v[e];
            }
#pragma unroll
            for (int j = (CN / 4) * 4; j < CN; ++j) rv[j] = row[j];
        } else {
            for (int j = 0; j < C; ++j) rv[j] = row[j];
        }
    };
    if (pv_[0]) loadrow(rvA, p_[0]);  // slot0 row latency hides under phase A

    s_h[tid] = 0;  // TPB == 256: one bin each
    for (int o = tid; o < O; o += TPB) {
        const float* t = targets + ((size_t)b * O + o) * 5;
        float x0 = t[0], y0 = t[1], x1 = t[2], y1 = t[3];
        s_tx0[o] = x0; s_ty0[o] = y0; s_tx1[o] = x1; s_ty1[o] = y1;
        s_lab[o] = t[4];
        s_area[o] = (x1 - x0) * (y1 - y0);
    }
    __syncthreads();

    // ---- phase A: jac sweep. per-slot tentative best (strict >, earliest o)
    //      + per-o wave argmax over 4 slots, lane0 key -> global ----
    float bto[SLOTS];
    int bti[SLOTS];
#pragma unroll
    for (int s = 0; s < SLOTS; ++s) { bto[s] = -1.0f; bti[s] = 0; }
    for (int o = 0; o < O; ++o) {
        float tx0 = s_tx0[o], ty0 = s_ty0[o], tx1 = s_tx1[o], ty1 = s_ty1[o], ta = s_area[o];
        float ov[SLOTS];
#pragma unroll
        for (int s = 0; s < SLOTS; ++s) {
            ov[s] = pv_[s] ? jac(tx0, ty0, tx1, ty1, ta,
                                 px0[s], py0[s], px1[s], py1[s], pa[s])
                           : -1.0f;
            if (ov[s] > bto[s]) { bto[s] = ov[s]; bti[s] = o; }
        }
        float mx = fmaxf(fmaxf(ov[0], ov[1]), fmaxf(ov[2], ov[3]));
#pragma unroll
        for (int d = 1; d < 64; d <<= 1)
            mx = fmaxf(mx, __shfl_xor(mx, d, 64));
        ull kk = 0ull;
        if (mx >= 0.0f) {  // wave-uniform
            ull m0 = __ballot(ov[0] == mx);
            int ss = 0;
            if (!m0) { m0 = __ballot(ov[1] == mx); ss = 1; }
            if (!m0) { m0 = __ballot(ov[2] == mx); ss = 2; }
            if (!m0) { m0 = __ballot(ov[3] == mx); ss = 3; }
            int src = __ffsll(m0) - 1;  // lowest lane in winning slot
            unsigned pw_ = (unsigned)(base + ss * TPB + (wv << 6) + src);
            kk = ((ull)__float_as_uint(mx) << 32) | (ull)(0xFFFFFFFFu - pw_);
        }
        if (lane == 0)
            pkeys[((size_t)b * O + o) * CB2P + chunk * WPB + wv] = kk;
    }

    // ---- phase B: per-slot conf LSE + tentative mined / sl1 / pos sums.
    // __expf/__logf identical (same intrinsic, same order) to select's fixup.
    float ll[SLOTS], pc[SLOTS];
    int np[SLOTS];
    auto doSlot = [&](int s, float* rv) {
        ll[s] = 0.0f; pc[s] = 0.0f; np[s] = 0;
        bool hv = false;
        int bn = 0;
        if (pv_[s]) {
            float m = rv[0];
#pragma unroll
            for (int j = 1; j < CC; ++j) { if (CN > 0 || j < C) m = fmaxf(m, rv[j]); }
            float sm = 0.0f;
#pragma unroll
            for (int j = 0; j < CC; ++j) { if (CN > 0 || j < C) sm += __expf(rv[j] - m); }
            float lse = m + __logf(sm);

            int c = (bto[s] < 0.5f) ? 0 : ((int)s_lab[bti[s]] + 1);
            float rowc = rv[0];
#pragma unroll
            for (int j = 1; j < CC; ++j) { if (CN > 0 || j < C) { if (c == j) rowc = rv[j]; } }
            float lc = lse - rowc;  // >= 0 always (sm >= 1)

            bool pos = c > 0;
            float mv = pos ? 0.0f : lc;
            mined[(size_t)b * P + p_[s]] = mv;
            bn = (int)(__float_as_uint(mv) >> 24);
            hv = true;
            if (pos) {
                pc[s] = lc;
                np[s] = 1;
                float4 pr = ((const float4*)priors)[p_[s]];  // L2-hot reload
                float cx = pr.x, cy = pr.y, pw = pr.z, ph = pr.w;
                float mx0 = s_tx0[bti[s]], my0 = s_ty0[bti[s]];
                float mx1 = s_tx1[bti[s]], my1 = s_ty1[bti[s]];
                float g0 = ((mx0 + mx1) * 0.5f - cx) / (0.1f * pw);
                float g1 = ((my0 + my1) * 0.5f - cy) / (0.1f * ph);
                float g2 = logf(fmaxf((mx1 - mx0) / pw, 1e-8f)) / 0.2f;
                float g3 = logf(fmaxf((my1 - my0) / ph, 1e-8f)) / 0.2f;
                float4 ld = ((const float4*)loc)[(size_t)b * P + p_[s]];
                float gt4[4] = {g0, g1, g2, g3};
                float lv[4] = {ld.x, ld.y, ld.z, ld.w};
#pragma unroll
                for (int q = 0; q < 4; ++q) {
                    float d = lv[q] - gt4[q];
                    float ad = fabsf(d);
                    ll[s] += (ad < 1.0f) ? 0.5f * d * d : (ad - 0.5f);
                }
            }
        }
        // top-byte histogram: wave-clustered LDS atomics (~few bins/wave)
        ull act = __ballot(hv);
        while (act) {
            int src = __ffsll(act) - 1;
            int b0 = __shfl(bn, src, 64);
            ull same = __ballot(hv && bn == b0) & act;
            if (lane == src) atomicAdd(&s_h[b0], (int)__popcll(same));
            act &= ~same;
        }
    };
    // software pipeline: load slot s+1's row while computing slot s
    if (pv_[1]) loadrow(rvB, p_[1]);
    doSlot(0, rvA);
    if (pv_[2]) loadrow(rvA, p_[2]);
    doSlot(1, rvB);
    if (pv_[3]) loadrow(rvB, p_[3]);
    doSlot(2, rvA);
    doSlot(3, rvB);

    // per-slot butterflies (256-prior chunk granularity -> bit-exact)
#pragma unroll
    for (int s = 0; s < SLOTS; ++s) {
        float l = ll[s], q = pc[s];
        int n = np[s];
#pragma unroll
        for (int d = 1; d < 64; d <<= 1) {
            l += __shfl_xor(l, d, 64);
            q += __shfl_xor(q, d, 64);
            n += __shfl_xor(n, d, 64);
        }
        if (lane == 0) { s_wll[wv][s] = l; s_wpc[wv][s] = q; s_wnp[wv][s] = n; }
    }
    __syncthreads();
    if (tid < SLOTS) {  // thread s sums slot s (same w=0..3 order as before)
        float L = 0.f, Pc = 0.f;
        int N = 0;
        for (int w = 0; w < WPB; ++w) { L += s_wll[w][tid]; Pc += s_wpc[w][tid]; N += s_wnp[w][tid]; }
        int pidx = b * CB2P + chunk * SLOTS + tid;
        part_ll[pidx] = L;
        part_pc[pidx] = Pc;
        part_np[pidx] = N;
    }
    if (tid < 128) {
        unsigned wd = (unsigned)s_h[2 * tid] | ((unsigned)s_h[2 * tid + 1] << 16);
        chist[((size_t)b * CB2 + chunk) * 128 + tid] = wd;
    }
}

// One 512-thread block per batch (R5: 8 waves -> every barrier ~2x cheaper
// than the 16-wave version; ~12 barriers on the critical path).
//  Values register-resident: thread owns indices tid + j*512, j<18.
//  BIT-EXACTNESS vs the 1024-thread version (whose tree matches reference):
//   - parts: only wave 0 holds nonzero partials (36 parts < 64 lanes); same
//     butterfly; trailing +0.0f adds are bitwise-neutral (partials >= 0).
//   - final sum DUAL-EMULATES the old tree: thread t' computes psumA over
//     even j (old thread t') and psumB over odd j (old thread t'+512), two
//     64-lane butterflies -> s_wf[w'] / s_wf[w'+8]; tid0 sums w=0..15 as
//     before -> identical values, identical order.
//   - all histogram/radix state is integer (order-free).
//  Radix scan is SINGLE-WAVE: lane l owns bins 4l..4l+3 (integer suffix +
//  6-shuffle wave suffix), writes s_bsel/s_krn directly — saves the s_wt
//  cross-wave stage and one barrier per pass.
//  sum(top-k) = sum_{>T} + (k-cnt_gt)*T — exact under ties.
template <int ON, int CN>
__global__ __launch_bounds__(TPBS) void select_kernel(
    const float* __restrict__ mined, const float* __restrict__ conf,
    const float* __restrict__ loc, const float* __restrict__ priors,
    const float* __restrict__ targets, const ull* __restrict__ pkeys,
    const float* __restrict__ part_ll, const float* __restrict__ part_pc,
    const int* __restrict__ part_np, const unsigned* __restrict__ chist,
    float* __restrict__ ll_batch, float* __restrict__ lc_batch,
    int* __restrict__ np_batch,
    int P, int O_rt, int C_rt, int CB2, int ratio) {
    constexpr int OMAX = (ON > 0) ? ON : 64;
    constexpr int NV = NVREG;
    const int O = (ON > 0) ? ON : O_rt;
    const int C = (CN > 0) ? CN : C_rt;
    const int b = blockIdx.x, tid = threadIdx.x;
    const int lane = tid & 63, wv = tid >> 6;
    constexpr int W = TPBS / 64;   // 8 waves
    const int CB2P = CB2 * SLOTS;  // part entries / per-wave key entries
    const float* v = mined + (size_t)b * P;
    const bool reg = (P <= NV * TPBS);

    __shared__ int s_hist[256];
    __shared__ float s_tx0[OMAX], s_ty0[OMAX], s_tx1[OMAX], s_ty1[OMAX];
    __shared__ float s_lab[OMAX], s_area[OMAX];
    __shared__ ull s_keys[OMAX];
    __shared__ int s_bp[OMAX];
    __shared__ float s_wf[16], s_wg[16];   // 16: old-tree emulation slots
    __shared__ int s_wi[16];
    __shared__ unsigned s_bsel;
    __shared__ int s_krn;
    __shared__ float s_bc[2], s_fix[2];
    __shared__ int s_bn, s_fixn;

    // 0. issue the row loads FIRST — latency hides under the reductions below
    float val[NV];
#pragma unroll
    for (int j = 0; j < NV; ++j) {
        int i = tid + j * TPBS;
        val[j] = (reg && i < P) ? v[i] : 0.0f;
    }

    // 1. per-chunk tentative partial reduction (parts 0..CB2P-1 all live in
    //    wave 0 when CB2P <= 64 -> identical tree to the 1024-thread version)
    float pll = 0.0f, ppc = 0.0f;
    int pnp = 0;
    for (int i = tid; i < CB2P; i += TPBS) {
        pll += part_ll[b * CB2P + i];
        ppc += part_pc[b * CB2P + i];
        pnp += part_np[b * CB2P + i];
    }
#pragma unroll
    for (int d = 1; d < 64; d <<= 1) {
        pll += __shfl_xor(pll, d, 64);
        ppc += __shfl_xor(ppc, d, 64);
        pnp += __shfl_xor(pnp, d, 64);
    }
    if (lane == 0) { s_wf[wv] = pll; s_wg[wv] = ppc; s_wi[wv] = pnp; }

    if (tid < O) {
        const float* t = targets + ((size_t)b * O + tid) * 5;
        float x0 = t[0], y0 = t[1], x1 = t[2], y1 = t[3];
        s_tx0[tid] = x0; s_ty0[tid] = y0; s_tx1[tid] = x1; s_ty1[tid] = y1;
        s_lab[tid] = t[4];
        s_area[tid] = (x1 - x0) * (y1 - y0);
        s_keys[tid] = 0ull;
    }
    __syncthreads();

    // 2. reduce per-wave keys (block-local LDS atomics, O*CB2P entries)
    for (int i = tid; i < O * CB2P; i += TPBS) {
        int o = i / CB2P, s = i % CB2P;
        atomicMax(&s_keys[o], pkeys[((size_t)b * O + o) * CB2P + s]);
    }
    __syncthreads();
    if (tid < O)
        s_bp[tid] = (int)(0xFFFFFFFFu - (unsigned)(s_keys[tid] & 0xFFFFFFFFull));
    __syncthreads();

    // zero forced priors in the register copy (forced -> positive -> mined 0)
    if (reg) {
#pragma unroll
        for (int j = 0; j < NV; ++j) {
            int i = tid + j * TPBS;
            bool z = false;
            for (int o = 0; o < O; ++o) z |= (s_bp[o] == i);
            if (z) val[j] = 0.0f;
        }
    }
    // one-time float->uint conversion for all radix passes
    unsigned uvv[NV];
#pragma unroll
    for (int j = 0; j < NV; ++j) uvv[j] = __float_as_uint(val[j]);

    // 2b. sum per-chunk top-byte histograms (bin = tid, u16 pair packed)
    if (tid < 256) {
        int h = 0;
        const unsigned* cb = chist + (size_t)b * CB2 * 128 + (tid >> 1);
        const int sh = (tid & 1) * 16;
        for (int c = 0; c < CB2; ++c) h += (int)((cb[c * 128] >> sh) & 0xFFFFu);
        s_hist[tid] = h;
    }

    // 3. FIXUP deltas (wave-0 lanes; proven bit-exact in R9/R11).
    float dll = 0.0f, dpc = 0.0f;
    int dnp = 0;
    int adj_bin = -1;  // hist adjustment: tentative value's top byte
    if (tid < O) {
        const int o = tid;
        const int p = s_bp[o];
        bool owner = true;
        for (int o2 = o + 1; o2 < O; ++o2)
            if (s_bp[o2] == p) owner = false;  // largest o owns (last-wins scatter)
        if (owner) {
            adj_bin = (int)(__float_as_uint(v[p]) >> 24);
            float4 pr = ((const float4*)priors)[p];
            float cx = pr.x, cy = pr.y, pw = pr.z, ph = pr.w;
            float px0 = cx - pw * 0.5f, py0 = cy - ph * 0.5f;
            float px1 = cx + pw * 0.5f, py1 = cy + ph * 0.5f;
            float pa = (px1 - px0) * (py1 - py0);
            float bto = -1.0f;
            int bti = 0;
            for (int o2 = 0; o2 < O; ++o2) {
                float ov = jac(s_tx0[o2], s_ty0[o2], s_tx1[o2], s_ty1[o2], s_area[o2],
                               px0, py0, px1, py1, pa);
                if (ov > bto) { bto = ov; bti = o2; }
            }
            int c_t = (bto < 0.5f) ? 0 : ((int)s_lab[bti] + 1);
            const float* row = conf + ((size_t)b * P + p) * C;
            float m = row[0];
            for (int j = 1; j < C; ++j) m = fmaxf(m, row[j]);
            float s = 0.0f;
            for (int j = 0; j < C; ++j) s += __expf(row[j] - m);
            float lse = m + __logf(s);
            int c_n = (int)s_lab[o] + 1;
            float lc_n = lse - row[c_n];
            bool pos_t = c_t > 0;
            float lc_t = lse - row[c_t];
            dpc = lc_n - (pos_t ? lc_t : 0.0f);
            dnp = 1 - (pos_t ? 1 : 0);
            float4 ld = ((const float4*)loc)[(size_t)b * P + p];
            float lv[4] = {ld.x, ld.y, ld.z, ld.w};
            float sl_new = 0.0f, sl_old = 0.0f;
            {
                float mx0 = s_tx0[o], my0 = s_ty0[o], mx1 = s_tx1[o], my1 = s_ty1[o];
                float g[4] = {((mx0 + mx1) * 0.5f - cx) / (0.1f * pw),
                              ((my0 + my1) * 0.5f - cy) / (0.1f * ph),
                              logf(fmaxf((mx1 - mx0) / pw, 1e-8f)) / 0.2f,
                              logf(fmaxf((my1 - my0) / ph, 1e-8f)) / 0.2f};
                for (int q = 0; q < 4; ++q) {
                    float d = lv[q] - g[q];
                    float ad = fabsf(d);
                    sl_new += (ad < 1.0f) ? 0.5f * d * d : (ad - 0.5f);
                }
            }
            if (pos_t) {
                float mx0 = s_tx0[bti], my0 = s_ty0[bti], mx1 = s_tx1[bti], my1 = s_ty1[bti];
                float g[4] = {((mx0 + mx1) * 0.5f - cx) / (0.1f * pw),
                              ((my0 + my1) * 0.5f - cy) / (0.1f * ph),
                              logf(fmaxf((mx1 - mx0) / pw, 1e-8f)) / 0.2f,
                              logf(fmaxf((my1 - my0) / ph, 1e-8f)) / 0.2f};
                for (int q = 0; q < 4; ++q) {
                    float d = lv[q] - g[q];
                    float ad = fabsf(d);
                    sl_old += (ad < 1.0f) ? 0.5f * d * d : (ad - 0.5f);
                }
            }
            dll = sl_new - sl_old;
        }
    }
    if (wv == 0) {
#pragma unroll
        for (int d = 1; d < 64; d <<= 1) {
            dll += __shfl_xor(dll, d, 64);
            dpc += __shfl_xor(dpc, d, 64);
            dnp += __shfl_xor(dnp, d, 64);
        }
        if (lane == 0) { s_fix[0] = dll; s_fix[1] = dpc; s_fixn = dnp; }
    }
    __syncthreads();
    // forced-zero hist adjustment (owners; matches zeroed registers exactly)
    if (adj_bin > 0) {  // adj_bin==0: -1/+1 on bin 0 cancels, skip
        atomicAdd(&s_hist[adj_bin], -1);
        atomicAdd(&s_hist[0], 1);
    }
    if (tid == 0) {
        float L = 0.f, Pc = 0.f;
        int N = 0;
        for (int w = 0; w < W; ++w) { L += s_wf[w]; Pc += s_wg[w]; N += s_wi[w]; }
        s_bc[0] = L + s_fix[0]; s_bc[1] = Pc + s_fix[1]; s_bn = N + s_fixn;
    }
    __syncthreads();
    const float ll_sum = s_bc[0];
    const float sum_pos = s_bc[1];
    const int npos = s_bn;

    const int k = min(ratio * npos, P - npos);
    if (tid == 0) {
        ll_batch[b] = ll_sum;
        np_batch[b] = npos;
    }
    if (k <= 0) {
        if (tid == 0) lc_batch[b] = sum_pos;
        return;
    }

    // 4. radix-select: pass 0 scan uses the precomputed+adjusted hist;
    //    passes 1-3 build a fresh single hist from the register copy.
    //    Scan is single-wave (lane l owns bins 4l..4l+3).
    unsigned prefix = 0u;
    int kr = k;
    for (int pass = 0; pass < 4; ++pass) {
        const int shift = 24 - 8 * pass;
        if (pass > 0) {
            const unsigned mask = 0xFFFFFFFFu << (32 - 8 * pass);
            if (tid < 256) s_hist[tid] = 0;
            __syncthreads();
            if (reg) {
#pragma unroll
                for (int j = 0; j < NV; ++j) {
                    int i = tid + j * TPBS;
                    unsigned u = uvv[j];
                    if (i < P && (u & mask) == prefix)
                        atomicAdd(&s_hist[(u >> shift) & 0xFF], 1);
                }
            } else {
                for (int i = tid; i < P; i += TPBS) {
                    float x = v[i];
                    for (int o = 0; o < O; ++o)
                        if (i == s_bp[o]) x = 0.0f;
                    unsigned u = __float_as_uint(x);
                    if ((u & mask) == prefix)
                        atomicAdd(&s_hist[(u >> shift) & 0xFF], 1);
                }
            }
            __syncthreads();
        }
        if (wv == 0) {
            int h0 = s_hist[4 * lane], h1 = s_hist[4 * lane + 1];
            int h2 = s_hist[4 * lane + 2], h3 = s_hist[4 * lane + 3];
            int s3 = h3, s2 = h2 + s3, s1 = h1 + s2, s0 = h0 + s1;
            int tot = s0, Sl = tot;
#pragma unroll
            for (int d = 1; d < 64; d <<= 1) {
                int t = __shfl_down(Sl, d, 64);
                if (lane + d < 64) Sl += t;
            }
            int above = Sl - tot;  // sum over lanes > lane
            int sg[4] = {above + s0, above + s1, above + s2, above + s3};
            int hh[4] = {h0, h1, h2, h3};
#pragma unroll
            for (int e = 0; e < 4; ++e) {
                int sge = sg[e], sgt = sge - hh[e];
                if (sge >= kr && sgt < kr) {  // exactly one (lane,e) satisfies
                    s_bsel = (unsigned)(4 * lane + e);
                    s_krn = kr - sgt;
                }
            }
        }
        __syncthreads();
        prefix |= s_bsel << shift;
        kr = s_krn;
        // next pass's clear happens after a barrier; s_bsel/s_krn rewritten
        // only after two more barriers — no hazard
    }
    const float T = __uint_as_float(prefix);  // exact k-th largest value
    // final sum: dual-emulate the 1024-thread tree (psumA = old thread tid,
    // psumB = old thread tid+512); s_wf[wv] = A, s_wf[wv+8] = B.
    float lsA = 0.0f, lsB = 0.0f;
    int lcA = 0, lcB = 0;
    if (reg) {
#pragma unroll
        for (int j = 0; j < NV; j += 2) {
            int i = tid + j * TPBS;
            if (i < P && val[j] > T) { lsA += val[j]; ++lcA; }
        }
#pragma unroll
        for (int j = 1; j < NV; j += 2) {
            int i = tid + j * TPBS;
            if (i < P && val[j] > T) { lsB += val[j]; ++lcB; }
        }
    } else {
        for (int i = tid; i < P; i += TPBS) {
            float x = v[i];
            for (int o = 0; o < O; ++o)
                if (i == s_bp[o]) x = 0.0f;
            if (x > T) { lsA += x; ++lcA; }
        }
    }
#pragma unroll
    for (int d = 1; d < 64; d <<= 1) {
        lsA += __shfl_xor(lsA, d, 64);
        lsB += __shfl_xor(lsB, d, 64);
        lcA += __shfl_xor(lcA, d, 64);
        lcB += __shfl_xor(lcB, d, 64);
    }
    if (lane == 0) {
        s_wf[wv] = lsA; s_wi[wv] = lcA;
        s_wf[wv + 8] = lsB; s_wi[wv + 8] = lcB;
    }
    __syncthreads();
    if (tid == 0) {
        float S = 0.f;
        int Cn = 0;
        for (int w = 0; w < 16; ++w) { S += s_wf[w]; Cn += s_wi[w]; }
        lc_batch[b] = sum_pos + S + (float)(k - Cn) * T;
    }
}

__global__ __launch_bounds__(256) void finalize_kernel(
    const float* __restrict__ ll_batch, const int* __restrict__ np_batch,
    const float* __restrict__ lc_batch, int B, float* __restrict__ out) {
    const int tid = threadIdx.x;
    __shared__ float s_l[256], s_c[256];
    __shared__ int s_n[256];
    float l = 0.0f, c = 0.0f;
    int n = 0;
    for (int i = tid; i < B; i += 256) {
        l += ll_batch[i];
        c += lc_batch[i];
        n += np_batch[i];
    }
    s_l[tid] = l; s_c[tid] = c; s_n[tid] = n;
    __syncthreads();
    for (int s = 256 / 2; s > 0; s >>= 1) {
        if (tid < s) {
            s_l[tid] += s_l[tid + s];
            s_c[tid] += s_c[tid + s];
            s_n[tid] += s_n[tid + s];
        }
        __syncthreads();
    }
    if (tid == 0) {
        float N = (float)s_n[0];
        out[0] = s_l[0] / N;
        out[1] = s_c[0] / N;
    }
}

extern "C" void kernel_launch(void* const* d_in, const int* in_sizes, int n_in,
                              void* d_out, int out_size, void* d_ws, size_t ws_size,
                              hipStream_t stream) {
    const float* loc = (const float*)d_in[0];
    const float* conf = (const float*)d_in[1];
    const float* priors = (const float*)d_in[2];
    const float* targets = (const float*)d_in[3];

    const int P = in_sizes[2] / 4;
    const int B = in_sizes[0] / (P * 4);
    const int C = in_sizes[1] / (in_sizes[0] / 4);  // conf / (B*P)
    const int O = in_sizes[3] / (B * 5);
    const size_t BP = (size_t)B * P;
    const int CB2 = (P + TPB * SLOTS - 1) / (TPB * SLOTS);  // 1024-prior chunks
    const int CB2P = CB2 * SLOTS;                            // 256-prior parts/keys

    // ws layout (8B-aligned first; everything fully written before read):
    ull* pkeys = (ull*)d_ws;                                  // B*O*CB2P u64
    float* mined = (float*)(pkeys + (size_t)B * O * CB2P);    // BP f32
    float* part_ll = mined + BP;                              // B*CB2P f32
    float* part_pc = part_ll + (size_t)B * CB2P;              // B*CB2P f32
    int* part_np = (int*)(part_pc + (size_t)B * CB2P);        // B*CB2P i32
    unsigned* chist = (unsigned*)(part_np + (size_t)B * CB2P);   // B*CB2*128 u32
    float* ll_batch = (float*)(chist + (size_t)B * CB2 * 128);   // B f32
    float* lc_batch = ll_batch + B;                           // B f32
    int* np_batch = (int*)(lc_batch + B);                     // B i32

    if (O == 8 && C == 21) {
        fused_kernel<8, 21><<<B * CB2, TPB, 0, stream>>>(
            loc, priors, targets, conf, P, O, C, CB2,
            mined, pkeys, part_ll, part_pc, part_np, chist);
        select_kernel<8, 21><<<B, TPBS, 0, stream>>>(
            mined, conf, loc, priors, targets, pkeys, part_ll, part_pc, part_np,
            chist, ll_batch, lc_batch, np_batch, P, O, C, CB2, 3);
    } else {
        fused_kernel<0, 0><<<B * CB2, TPB, 0, stream>>>(
            loc, priors, targets, conf, P, O, C, CB2,
            mined, pkeys, part_ll, part_pc, part_np, chist);
        select_kernel<0, 0><<<B, TPBS, 0, stream>>>(
            mined, conf, loc, priors, targets, pkeys, part_ll, part_pc, part_np,
            chist, ll_batch, lc_batch, np_batch, P, O, C, CB2, 3);
    }

    finalize_kernel<<<1, 256, 0, stream>>>(ll_batch, np_batch, lc_batch, B,
                                           (float*)d_out);
}

// Round 6
// 118.508 us; speedup vs baseline: 1.0186x; 1.0186x over previous
//
#include <hip/hip_runtime.h>
#include <math.h>

#define TPB 256
#define SLOTS 4      // priors per fused thread (wave argmax covers 256 priors)
#define TPBS 1024    // select block size (R6: back to R4 — TLP for val loads)
#define NVREG 9      // register slots/thread in select (covers P <= 9216)

typedef unsigned long long ull;
typedef float pf4 __attribute__((ext_vector_type(4), aligned(4)));  // 4B-aligned float4

__device__ __forceinline__ float jac(float tx0, float ty0, float tx1, float ty1, float ta,
                                     float px0, float py0, float px1, float py1, float pa) {
    float ltx = fmaxf(tx0, px0), lty = fmaxf(ty0, py0);
    float rbx = fminf(tx1, px1), rby = fminf(ty1, py1);
    float w = fmaxf(rbx - ltx, 0.0f), h = fmaxf(rby - lty, 0.0f);
    float inter = w * h;
    return inter / (ta + pa - inter);
}

// R4 (kept): 4 priors/thread (slot s owns p = chunk*1024 + s*256 + tid).
//  - per-o argmax: one 6-level wave shuffle covers 256 priors; slot-ordered
//    ballots keep the exact smallest-p tie.
//  - part sums keep the 256-prior chunk granularity (one butterfly per slot,
//    same w=0..3 add order) -> every fp summation tree bit-identical.
//  - conf rows software-pipelined through rvA/rvB.
//  - per-chunk (1024-prior) top-byte histogram, u16-pair packed.
template <int ON, int CN>
__global__ __launch_bounds__(TPB) void fused_kernel(
    const float* __restrict__ loc, const float* __restrict__ priors,
    const float* __restrict__ targets, const float* __restrict__ conf,
    int P, int O_rt, int C_rt, int CB2,
    float* __restrict__ mined, ull* __restrict__ pkeys,
    float* __restrict__ part_ll, float* __restrict__ part_pc,
    int* __restrict__ part_np, unsigned* __restrict__ chist) {
    constexpr int OMAX = (ON > 0) ? ON : 64;
    constexpr int CC = (CN > 0) ? CN : 32;
    constexpr int WPB = TPB / 64;  // 4 waves per block
    const int O = (ON > 0) ? ON : O_rt;
    const int C = (CN > 0) ? CN : C_rt;
    const int b = blockIdx.x / CB2;
    const int chunk = blockIdx.x % CB2;
    const int tid = threadIdx.x;
    const int base = chunk * (TPB * SLOTS);
    const int lane = tid & 63, wv = tid >> 6;
    const int CB2P = CB2 * SLOTS;  // per-wave key entries / old-chunk parts

    __shared__ float s_tx0[OMAX], s_ty0[OMAX], s_tx1[OMAX], s_ty1[OMAX];
    __shared__ float s_lab[OMAX], s_area[OMAX];
    __shared__ int s_h[256];
    __shared__ float s_wll[WPB][SLOTS], s_wpc[WPB][SLOTS];
    __shared__ int s_wnp[WPB][SLOTS];

    int p_[SLOTS];
    bool pv_[SLOTS];
#pragma unroll
    for (int s = 0; s < SLOTS; ++s) { p_[s] = base + s * TPB + tid; pv_[s] = p_[s] < P; }

    // prior corners (issued first; cx/cy/pw/ph reloaded L2-hot in phase B)
    float px0[SLOTS], py0[SLOTS], px1[SLOTS], py1[SLOTS], pa[SLOTS];
#pragma unroll
    for (int s = 0; s < SLOTS; ++s) {
        float4 pr = pv_[s] ? ((const float4*)priors)[p_[s]] : make_float4(0.f, 0.f, 1.f, 1.f);
        px0[s] = pr.x - pr.z * 0.5f; py0[s] = pr.y - pr.w * 0.5f;
        px1[s] = pr.x + pr.z * 0.5f; py1[s] = pr.y + pr.w * 0.5f;
        pa[s] = (px1[s] - px0[s]) * (py1[s] - py0[s]);
    }

    float rvA[CC], rvB[CC];
    auto loadrow = [&](float* rv, int p) {
        const float* row = conf + ((size_t)b * P + p) * C;
        if (CN > 0) {
#pragma unroll
            for (int q = 0; q < CN / 4; ++q) {
                pf4 v = *(const pf4*)(row + 4 * q);
#pragma unroll
                for (int e = 0; e < 4; ++e) rv[4 * q + e] = v[e];
            }
#pragma unroll
            for (int j = (CN / 4) * 4; j < CN; ++j) rv[j] = row[j];
        } else {
            for (int j = 0; j < C; ++j) rv[j] = row[j];
        }
    };
    if (pv_[0]) loadrow(rvA, p_[0]);  // slot0 row latency hides under phase A

    s_h[tid] = 0;  // TPB == 256: one bin each
    for (int o = tid; o < O; o += TPB) {
        const float* t = targets + ((size_t)b * O + o) * 5;
        float x0 = t[0], y0 = t[1], x1 = t[2], y1 = t[3];
        s_tx0[o] = x0; s_ty0[o] = y0; s_tx1[o] = x1; s_ty1[o] = y1;
        s_lab[o] = t[4];
        s_area[o] = (x1 - x0) * (y1 - y0);
    }
    __syncthreads();

    // ---- phase A: jac sweep. per-slot tentative best (strict >, earliest o)
    //      + per-o wave argmax over 4 slots, lane0 key -> global ----
    float bto[SLOTS];
    int bti[SLOTS];
#pragma unroll
    for (int s = 0; s < SLOTS; ++s) { bto[s] = -1.0f; bti[s] = 0; }
    for (int o = 0; o < O; ++o) {
        float tx0 = s_tx0[o], ty0 = s_ty0[o], tx1 = s_tx1[o], ty1 = s_ty1[o], ta = s_area[o];
        float ov[SLOTS];
#pragma unroll
        for (int s = 0; s < SLOTS; ++s) {
            ov[s] = pv_[s] ? jac(tx0, ty0, tx1, ty1, ta,
                                 px0[s], py0[s], px1[s], py1[s], pa[s])
                           : -1.0f;
            if (ov[s] > bto[s]) { bto[s] = ov[s]; bti[s] = o; }
        }
        float mx = fmaxf(fmaxf(ov[0], ov[1]), fmaxf(ov[2], ov[3]));
#pragma unroll
        for (int d = 1; d < 64; d <<= 1)
            mx = fmaxf(mx, __shfl_xor(mx, d, 64));
        ull kk = 0ull;
        if (mx >= 0.0f) {  // wave-uniform
            ull m0 = __ballot(ov[0] == mx);
            int ss = 0;
            if (!m0) { m0 = __ballot(ov[1] == mx); ss = 1; }
            if (!m0) { m0 = __ballot(ov[2] == mx); ss = 2; }
            if (!m0) { m0 = __ballot(ov[3] == mx); ss = 3; }
            int src = __ffsll(m0) - 1;  // lowest lane in winning slot
            unsigned pw_ = (unsigned)(base + ss * TPB + (wv << 6) + src);
            kk = ((ull)__float_as_uint(mx) << 32) | (ull)(0xFFFFFFFFu - pw_);
        }
        if (lane == 0)
            pkeys[((size_t)b * O + o) * CB2P + chunk * WPB + wv] = kk;
    }

    // ---- phase B: per-slot conf LSE + tentative mined / sl1 / pos sums.
    // __expf/__logf identical (same intrinsic, same order) to select's fixup.
    float ll[SLOTS], pc[SLOTS];
    int np[SLOTS];
    auto doSlot = [&](int s, float* rv) {
        ll[s] = 0.0f; pc[s] = 0.0f; np[s] = 0;
        bool hv = false;
        int bn = 0;
        if (pv_[s]) {
            float m = rv[0];
#pragma unroll
            for (int j = 1; j < CC; ++j) { if (CN > 0 || j < C) m = fmaxf(m, rv[j]); }
            float sm = 0.0f;
#pragma unroll
            for (int j = 0; j < CC; ++j) { if (CN > 0 || j < C) sm += __expf(rv[j] - m); }
            float lse = m + __logf(sm);

            int c = (bto[s] < 0.5f) ? 0 : ((int)s_lab[bti[s]] + 1);
            float rowc = rv[0];
#pragma unroll
            for (int j = 1; j < CC; ++j) { if (CN > 0 || j < C) { if (c == j) rowc = rv[j]; } }
            float lc = lse - rowc;  // >= 0 always (sm >= 1)

            bool pos = c > 0;
            float mv = pos ? 0.0f : lc;
            mined[(size_t)b * P + p_[s]] = mv;
            bn = (int)(__float_as_uint(mv) >> 24);
            hv = true;
            if (pos) {
                pc[s] = lc;
                np[s] = 1;
                float4 pr = ((const float4*)priors)[p_[s]];  // L2-hot reload
                float cx = pr.x, cy = pr.y, pw = pr.z, ph = pr.w;
                float mx0 = s_tx0[bti[s]], my0 = s_ty0[bti[s]];
                float mx1 = s_tx1[bti[s]], my1 = s_ty1[bti[s]];
                float g0 = ((mx0 + mx1) * 0.5f - cx) / (0.1f * pw);
                float g1 = ((my0 + my1) * 0.5f - cy) / (0.1f * ph);
                float g2 = logf(fmaxf((mx1 - mx0) / pw, 1e-8f)) / 0.2f;
                float g3 = logf(fmaxf((my1 - my0) / ph, 1e-8f)) / 0.2f;
                float4 ld = ((const float4*)loc)[(size_t)b * P + p_[s]];
                float gt4[4] = {g0, g1, g2, g3};
                float lv[4] = {ld.x, ld.y, ld.z, ld.w};
#pragma unroll
                for (int q = 0; q < 4; ++q) {
                    float d = lv[q] - gt4[q];
                    float ad = fabsf(d);
                    ll[s] += (ad < 1.0f) ? 0.5f * d * d : (ad - 0.5f);
                }
            }
        }
        // top-byte histogram: wave-clustered LDS atomics (~few bins/wave)
        ull act = __ballot(hv);
        while (act) {
            int src = __ffsll(act) - 1;
            int b0 = __shfl(bn, src, 64);
            ull same = __ballot(hv && bn == b0) & act;
            if (lane == src) atomicAdd(&s_h[b0], (int)__popcll(same));
            act &= ~same;
        }
    };
    // software pipeline: load slot s+1's row while computing slot s
    if (pv_[1]) loadrow(rvB, p_[1]);
    doSlot(0, rvA);
    if (pv_[2]) loadrow(rvA, p_[2]);
    doSlot(1, rvB);
    if (pv_[3]) loadrow(rvB, p_[3]);
    doSlot(2, rvA);
    doSlot(3, rvB);

    // per-slot butterflies (256-prior chunk granularity -> bit-exact)
#pragma unroll
    for (int s = 0; s < SLOTS; ++s) {
        float l = ll[s], q = pc[s];
        int n = np[s];
#pragma unroll
        for (int d = 1; d < 64; d <<= 1) {
            l += __shfl_xor(l, d, 64);
            q += __shfl_xor(q, d, 64);
            n += __shfl_xor(n, d, 64);
        }
        if (lane == 0) { s_wll[wv][s] = l; s_wpc[wv][s] = q; s_wnp[wv][s] = n; }
    }
    __syncthreads();
    if (tid < SLOTS) {  // thread s sums slot s (same w=0..3 order as before)
        float L = 0.f, Pc = 0.f;
        int N = 0;
        for (int w = 0; w < WPB; ++w) { L += s_wll[w][tid]; Pc += s_wpc[w][tid]; N += s_wnp[w][tid]; }
        int pidx = b * CB2P + chunk * SLOTS + tid;
        part_ll[pidx] = L;
        part_pc[pidx] = Pc;
        part_np[pidx] = N;
    }
    if (tid < 128) {
        unsigned wd = (unsigned)s_h[2 * tid] | ((unsigned)s_h[2 * tid + 1] << 16);
        chist[((size_t)b * CB2 + chunk) * 128 + tid] = wd;
    }
}

// One 1024-thread block per batch (R4 config restored — the 512-thread
// variant regressed: halved TLP on the val[] stage cost more than the
// barriers saved). R6 keeps ONLY the single-wave radix scan from R5:
// lane l of wave 0 owns bins 4l..4l+3 -> no s_wt cross-wave stage, one
// fewer barrier per pass. Scan state is integer -> bit-identical.
//  Values register-resident: thread owns indices tid + j*1024, j<9.
//  Radix pass 0 precomputed from fused's per-chunk top-byte histograms
//  (+ forced-zero adjustment); passes 1-3 single 256-int hist.
//  sum(top-k) = sum_{>T} + (k-cnt_gt)*T — exact under ties.
template <int ON, int CN>
__global__ __launch_bounds__(TPBS) void select_kernel(
    const float* __restrict__ mined, const float* __restrict__ conf,
    const float* __restrict__ loc, const float* __restrict__ priors,
    const float* __restrict__ targets, const ull* __restrict__ pkeys,
    const float* __restrict__ part_ll, const float* __restrict__ part_pc,
    const int* __restrict__ part_np, const unsigned* __restrict__ chist,
    float* __restrict__ ll_batch, float* __restrict__ lc_batch,
    int* __restrict__ np_batch,
    int P, int O_rt, int C_rt, int CB2, int ratio) {
    constexpr int OMAX = (ON > 0) ? ON : 64;
    constexpr int NV = NVREG;
    const int O = (ON > 0) ? ON : O_rt;
    const int C = (CN > 0) ? CN : C_rt;
    const int b = blockIdx.x, tid = threadIdx.x;
    const int lane = tid & 63, wv = tid >> 6;
    constexpr int W = TPBS / 64;   // 16 waves
    const int CB2P = CB2 * SLOTS;  // part entries / per-wave key entries
    const float* v = mined + (size_t)b * P;
    const bool reg = (P <= NV * TPBS);

    __shared__ int s_hist[256];
    __shared__ float s_tx0[OMAX], s_ty0[OMAX], s_tx1[OMAX], s_ty1[OMAX];
    __shared__ float s_lab[OMAX], s_area[OMAX];
    __shared__ ull s_keys[OMAX];
    __shared__ int s_bp[OMAX];
    __shared__ float s_wf[W], s_wg[W];
    __shared__ int s_wi[W];
    __shared__ unsigned s_bsel;
    __shared__ int s_krn;
    __shared__ float s_bc[2], s_fix[2];
    __shared__ int s_bn, s_fixn;

    // 0. issue the row loads FIRST — latency hides under the reductions below
    float val[NV];
#pragma unroll
    for (int j = 0; j < NV; ++j) {
        int i = tid + j * TPBS;
        val[j] = (reg && i < P) ? v[i] : 0.0f;
    }

    // 1. per-chunk tentative partial reduction
    float pll = 0.0f, ppc = 0.0f;
    int pnp = 0;
    for (int i = tid; i < CB2P; i += TPBS) {
        pll += part_ll[b * CB2P + i];
        ppc += part_pc[b * CB2P + i];
        pnp += part_np[b * CB2P + i];
    }
#pragma unroll
    for (int d = 1; d < 64; d <<= 1) {
        pll += __shfl_xor(pll, d, 64);
        ppc += __shfl_xor(ppc, d, 64);
        pnp += __shfl_xor(pnp, d, 64);
    }
    if (lane == 0) { s_wf[wv] = pll; s_wg[wv] = ppc; s_wi[wv] = pnp; }

    if (tid < O) {
        const float* t = targets + ((size_t)b * O + tid) * 5;
        float x0 = t[0], y0 = t[1], x1 = t[2], y1 = t[3];
        s_tx0[tid] = x0; s_ty0[tid] = y0; s_tx1[tid] = x1; s_ty1[tid] = y1;
        s_lab[tid] = t[4];
        s_area[tid] = (x1 - x0) * (y1 - y0);
        s_keys[tid] = 0ull;
    }
    __syncthreads();

    // 2. reduce per-wave keys (block-local LDS atomics, O*CB2P entries)
    for (int i = tid; i < O * CB2P; i += TPBS) {
        int o = i / CB2P, s = i % CB2P;
        atomicMax(&s_keys[o], pkeys[((size_t)b * O + o) * CB2P + s]);
    }
    __syncthreads();
    if (tid < O)
        s_bp[tid] = (int)(0xFFFFFFFFu - (unsigned)(s_keys[tid] & 0xFFFFFFFFull));
    __syncthreads();

    // zero forced priors in the register copy (forced -> positive -> mined 0)
    if (reg) {
#pragma unroll
        for (int j = 0; j < NV; ++j) {
            int i = tid + j * TPBS;
            bool z = false;
            for (int o = 0; o < O; ++o) z |= (s_bp[o] == i);
            if (z) val[j] = 0.0f;
        }
    }
    // one-time float->uint conversion for all radix passes
    unsigned uvv[NV];
#pragma unroll
    for (int j = 0; j < NV; ++j) uvv[j] = __float_as_uint(val[j]);

    // 2b. sum per-chunk top-byte histograms (bin = tid, u16 pair packed)
    if (tid < 256) {
        int h = 0;
        const unsigned* cb = chist + (size_t)b * CB2 * 128 + (tid >> 1);
        const int sh = (tid & 1) * 16;
        for (int c = 0; c < CB2; ++c) h += (int)((cb[c * 128] >> sh) & 0xFFFFu);
        s_hist[tid] = h;
    }

    // 3. FIXUP deltas (wave-0 lanes; proven bit-exact in R9/R11).
    float dll = 0.0f, dpc = 0.0f;
    int dnp = 0;
    int adj_bin = -1;  // hist adjustment: tentative value's top byte
    if (tid < O) {
        const int o = tid;
        const int p = s_bp[o];
        bool owner = true;
        for (int o2 = o + 1; o2 < O; ++o2)
            if (s_bp[o2] == p) owner = false;  // largest o owns (last-wins scatter)
        if (owner) {
            adj_bin = (int)(__float_as_uint(v[p]) >> 24);
            float4 pr = ((const float4*)priors)[p];
            float cx = pr.x, cy = pr.y, pw = pr.z, ph = pr.w;
            float px0 = cx - pw * 0.5f, py0 = cy - ph * 0.5f;
            float px1 = cx + pw * 0.5f, py1 = cy + ph * 0.5f;
            float pa = (px1 - px0) * (py1 - py0);
            float bto = -1.0f;
            int bti = 0;
            for (int o2 = 0; o2 < O; ++o2) {
                float ov = jac(s_tx0[o2], s_ty0[o2], s_tx1[o2], s_ty1[o2], s_area[o2],
                               px0, py0, px1, py1, pa);
                if (ov > bto) { bto = ov; bti = o2; }
            }
            int c_t = (bto < 0.5f) ? 0 : ((int)s_lab[bti] + 1);
            const float* row = conf + ((size_t)b * P + p) * C;
            float m = row[0];
            for (int j = 1; j < C; ++j) m = fmaxf(m, row[j]);
            float s = 0.0f;
            for (int j = 0; j < C; ++j) s += __expf(row[j] - m);
            float lse = m + __logf(s);
            int c_n = (int)s_lab[o] + 1;
            float lc_n = lse - row[c_n];
            bool pos_t = c_t > 0;
            float lc_t = lse - row[c_t];
            dpc = lc_n - (pos_t ? lc_t : 0.0f);
            dnp = 1 - (pos_t ? 1 : 0);
            float4 ld = ((const float4*)loc)[(size_t)b * P + p];
            float lv[4] = {ld.x, ld.y, ld.z, ld.w};
            float sl_new = 0.0f, sl_old = 0.0f;
            {
                float mx0 = s_tx0[o], my0 = s_ty0[o], mx1 = s_tx1[o], my1 = s_ty1[o];
                float g[4] = {((mx0 + mx1) * 0.5f - cx) / (0.1f * pw),
                              ((my0 + my1) * 0.5f - cy) / (0.1f * ph),
                              logf(fmaxf((mx1 - mx0) / pw, 1e-8f)) / 0.2f,
                              logf(fmaxf((my1 - my0) / ph, 1e-8f)) / 0.2f};
                for (int q = 0; q < 4; ++q) {
                    float d = lv[q] - g[q];
                    float ad = fabsf(d);
                    sl_new += (ad < 1.0f) ? 0.5f * d * d : (ad - 0.5f);
                }
            }
            if (pos_t) {
                float mx0 = s_tx0[bti], my0 = s_ty0[bti], mx1 = s_tx1[bti], my1 = s_ty1[bti];
                float g[4] = {((mx0 + mx1) * 0.5f - cx) / (0.1f * pw),
                              ((my0 + my1) * 0.5f - cy) / (0.1f * ph),
                              logf(fmaxf((mx1 - mx0) / pw, 1e-8f)) / 0.2f,
                              logf(fmaxf((my1 - my0) / ph, 1e-8f)) / 0.2f};
                for (int q = 0; q < 4; ++q) {
                    float d = lv[q] - g[q];
                    float ad = fabsf(d);
                    sl_old += (ad < 1.0f) ? 0.5f * d * d : (ad - 0.5f);
                }
            }
            dll = sl_new - sl_old;
        }
    }
    if (wv == 0) {
#pragma unroll
        for (int d = 1; d < 64; d <<= 1) {
            dll += __shfl_xor(dll, d, 64);
            dpc += __shfl_xor(dpc, d, 64);
            dnp += __shfl_xor(dnp, d, 64);
        }
        if (lane == 0) { s_fix[0] = dll; s_fix[1] = dpc; s_fixn = dnp; }
    }
    __syncthreads();
    // forced-zero hist adjustment (owners; matches zeroed registers exactly)
    if (adj_bin > 0) {  // adj_bin==0: -1/+1 on bin 0 cancels, skip
        atomicAdd(&s_hist[adj_bin], -1);
        atomicAdd(&s_hist[0], 1);
    }
    if (tid == 0) {
        float L = 0.f, Pc = 0.f;
        int N = 0;
        for (int w = 0; w < W; ++w) { L += s_wf[w]; Pc += s_wg[w]; N += s_wi[w]; }
        s_bc[0] = L + s_fix[0]; s_bc[1] = Pc + s_fix[1]; s_bn = N + s_fixn;
    }
    __syncthreads();
    const float ll_sum = s_bc[0];
    const float sum_pos = s_bc[1];
    const int npos = s_bn;

    const int k = min(ratio * npos, P - npos);
    if (tid == 0) {
        ll_batch[b] = ll_sum;
        np_batch[b] = npos;
    }
    if (k <= 0) {
        if (tid == 0) lc_batch[b] = sum_pos;
        return;
    }

    // 4. radix-select: pass 0 scan uses the precomputed+adjusted hist;
    //    passes 1-3 build a fresh single hist from the register copy.
    //    Scan is SINGLE-WAVE (lane l owns bins 4l..4l+3) — integer state,
    //    bit-identical; saves the cross-wave stage + 1 barrier per pass.
    unsigned prefix = 0u;
    int kr = k;
    for (int pass = 0; pass < 4; ++pass) {
        const int shift = 24 - 8 * pass;
        if (pass > 0) {
            const unsigned mask = 0xFFFFFFFFu << (32 - 8 * pass);
            if (tid < 256) s_hist[tid] = 0;
            __syncthreads();
            if (reg) {
#pragma unroll
                for (int j = 0; j < NV; ++j) {
                    int i = tid + j * TPBS;
                    unsigned u = uvv[j];
                    if (i < P && (u & mask) == prefix)
                        atomicAdd(&s_hist[(u >> shift) & 0xFF], 1);
                }
            } else {
                for (int i = tid; i < P; i += TPBS) {
                    float x = v[i];
                    for (int o = 0; o < O; ++o)
                        if (i == s_bp[o]) x = 0.0f;
                    unsigned u = __float_as_uint(x);
                    if ((u & mask) == prefix)
                        atomicAdd(&s_hist[(u >> shift) & 0xFF], 1);
                }
            }
            __syncthreads();
        }
        if (wv == 0) {
            int h0 = s_hist[4 * lane], h1 = s_hist[4 * lane + 1];
            int h2 = s_hist[4 * lane + 2], h3 = s_hist[4 * lane + 3];
            int s3 = h3, s2 = h2 + s3, s1 = h1 + s2, s0 = h0 + s1;
            int tot = s0, Sl = tot;
#pragma unroll
            for (int d = 1; d < 64; d <<= 1) {
                int t = __shfl_down(Sl, d, 64);
                if (lane + d < 64) Sl += t;
            }
            int above = Sl - tot;  // sum over lanes > lane
            int sg[4] = {above + s0, above + s1, above + s2, above + s3};
            int hh[4] = {h0, h1, h2, h3};
#pragma unroll
            for (int e = 0; e < 4; ++e) {
                int sge = sg[e], sgt = sge - hh[e];
                if (sge >= kr && sgt < kr) {  // exactly one (lane,e) satisfies
                    s_bsel = (unsigned)(4 * lane + e);
                    s_krn = kr - sgt;
                }
            }
        }
        __syncthreads();
        prefix |= s_bsel << shift;
        kr = s_krn;
        // next pass's clear happens after a barrier; s_bsel/s_krn rewritten
        // only after two more barriers — no hazard
    }
    const float T = __uint_as_float(prefix);  // exact k-th largest value
    float lsum = 0.0f;
    int lcnt = 0;
    if (reg) {
#pragma unroll
        for (int j = 0; j < NV; ++j) {
            int i = tid + j * TPBS;
            if (i < P && val[j] > T) { lsum += val[j]; ++lcnt; }
        }
    } else {
        for (int i = tid; i < P; i += TPBS) {
            float x = v[i];
            for (int o = 0; o < O; ++o)
                if (i == s_bp[o]) x = 0.0f;
            if (x > T) { lsum += x; ++lcnt; }
        }
    }
#pragma unroll
    for (int d = 1; d < 64; d <<= 1) {
        lsum += __shfl_xor(lsum, d, 64);
        lcnt += __shfl_xor(lcnt, d, 64);
    }
    if (lane == 0) { s_wf[wv] = lsum; s_wi[wv] = lcnt; }
    __syncthreads();
    if (tid == 0) {
        float S = 0.f;
        int Cn = 0;
        for (int w = 0; w < W; ++w) { S += s_wf[w]; Cn += s_wi[w]; }
        lc_batch[b] = sum_pos + S + (float)(k - Cn) * T;
    }
}

__global__ __launch_bounds__(256) void finalize_kernel(
    const float* __restrict__ ll_batch, const int* __restrict__ np_batch,
    const float* __restrict__ lc_batch, int B, float* __restrict__ out) {
    const int tid = threadIdx.x;
    __shared__ float s_l[256], s_c[256];
    __shared__ int s_n[256];
    float l = 0.0f, c = 0.0f;
    int n = 0;
    for (int i = tid; i < B; i += 256) {
        l += ll_batch[i];
        c += lc_batch[i];
        n += np_batch[i];
    }
    s_l[tid] = l; s_c[tid] = c; s_n[tid] = n;
    __syncthreads();
    for (int s = 256 / 2; s > 0; s >>= 1) {
        if (tid < s) {
            s_l[tid] += s_l[tid + s];
            s_c[tid] += s_c[tid + s];
            s_n[tid] += s_n[tid + s];
        }
        __syncthreads();
    }
    if (tid == 0) {
        float N = (float)s_n[0];
        out[0] = s_l[0] / N;
        out[1] = s_c[0] / N;
    }
}

extern "C" void kernel_launch(void* const* d_in, const int* in_sizes, int n_in,
                              void* d_out, int out_size, void* d_ws, size_t ws_size,
                              hipStream_t stream) {
    const float* loc = (const float*)d_in[0];
    const float* conf = (const float*)d_in[1];
    const float* priors = (const float*)d_in[2];
    const float* targets = (const float*)d_in[3];

    const int P = in_sizes[2] / 4;
    const int B = in_sizes[0] / (P * 4);
    const int C = in_sizes[1] / (in_sizes[0] / 4);  // conf / (B*P)
    const int O = in_sizes[3] / (B * 5);
    const size_t BP = (size_t)B * P;
    const int CB2 = (P + TPB * SLOTS - 1) / (TPB * SLOTS);  // 1024-prior chunks
    const int CB2P = CB2 * SLOTS;                            // 256-prior parts/keys

    // ws layout (8B-aligned first; everything fully written before read):
    ull* pkeys = (ull*)d_ws;                                  // B*O*CB2P u64
    float* mined = (float*)(pkeys + (size_t)B * O * CB2P);    // BP f32
    float* part_ll = mined + BP;                              // B*CB2P f32
    float* part_pc = part_ll + (size_t)B * CB2P;              // B*CB2P f32
    int* part_np = (int*)(part_pc + (size_t)B * CB2P);        // B*CB2P i32
    unsigned* chist = (unsigned*)(part_np + (size_t)B * CB2P);   // B*CB2*128 u32
    float* ll_batch = (float*)(chist + (size_t)B * CB2 * 128);   // B f32
    float* lc_batch = ll_batch + B;                           // B f32
    int* np_batch = (int*)(lc_batch + B);                     // B i32

    if (O == 8 && C == 21) {
        fused_kernel<8, 21><<<B * CB2, TPB, 0, stream>>>(
            loc, priors, targets, conf, P, O, C, CB2,
            mined, pkeys, part_ll, part_pc, part_np, chist);
        select_kernel<8, 21><<<B, TPBS, 0, stream>>>(
            mined, conf, loc, priors, targets, pkeys, part_ll, part_pc, part_np,
            chist, ll_batch, lc_batch, np_batch, P, O, C, CB2, 3);
    } else {
        fused_kernel<0, 0><<<B * CB2, TPB, 0, stream>>>(
            loc, priors, targets, conf, P, O, C, CB2,
            mined, pkeys, part_ll, part_pc, part_np, chist);
        select_kernel<0, 0><<<B, TPBS, 0, stream>>>(
            mined, conf, loc, priors, targets, pkeys, part_ll, part_pc, part_np,
            chist, ll_batch, lc_batch, np_batch, P, O, C, CB2, 3);
    }

    finalize_kernel<<<1, 256, 0, stream>>>(ll_batch, np_batch, lc_batch, B,
                                           (float*)d_out);
}